// Round 3
// baseline (1868.744 us; speedup 1.0000x reference)
//
#include <hip/hip_runtime.h>
#include <hip/hip_bf16.h>

// ---------------------------------------------------------------------------
// RNN_20572893348005: 2-layer tanh RNN, B=64 T=1024 D=128 H=256, out [B,H,T]
// Input dtype detected at runtime (bf16 vs f32) via exponent-field probe of
// W_hh0; all downstream kernels branch wave-uniformly on a flag in d_ws.
// Compute: f16 operands, fp32 accumulate (v_dot2_f32_f16).
//
// Time-chunked (ws_size-aware): per chunk c:
//   proj0 (K=128): xw = x_chunk @ W_ih0^T + b0    (bf16/f32 src -> f16)
//   scan0        : h0_chunk, carry0               (f16)
//   proj1 (K=256): xw = h0_chunk @ W_ih1^T + b1   (f16 -> f16)
//   scan1        : out[b][j][t] (bf16 or f32), carry1
// Scan: 1 WG/batch, thread j holds W_hh row j in VGPRs (32 uint4),
// h in LDS f16 double-buffered -> 1 barrier/step.
// ---------------------------------------------------------------------------

#define B_ 64
#define T_ 1024
#define D_ 128
#define H_ 256

typedef _Float16 half2_t __attribute__((ext_vector_type(2)));

__device__ __forceinline__ float bf2f(unsigned short u) {
    union { unsigned int i; float f; } v;
    v.i = ((unsigned int)u) << 16;
    return v.f;
}

__device__ __forceinline__ unsigned int cvt2_bf16_to_f16(unsigned int u) {
    union { float f; unsigned int i; } a, b;
    a.i = u << 16;
    b.i = u & 0xFFFF0000u;
    union { _Float16 h[2]; unsigned int u; } r;
    r.h[0] = (_Float16)a.f;
    r.h[1] = (_Float16)b.f;
    return r.u;
}

__device__ __forceinline__ uint4 cvt8_bf16_to_f16(uint4 v) {
    uint4 r;
    r.x = cvt2_bf16_to_f16(v.x);
    r.y = cvt2_bf16_to_f16(v.y);
    r.z = cvt2_bf16_to_f16(v.z);
    r.w = cvt2_bf16_to_f16(v.w);
    return r;
}

__device__ __forceinline__ float dot2(unsigned int a, unsigned int b, float c) {
    union { unsigned int u; half2_t h; } ua, ub;
    ua.u = a; ub.u = b;
#if defined(__HIP_DEVICE_COMPILE__) && __has_builtin(__builtin_amdgcn_fdot2)
    return __builtin_amdgcn_fdot2(ua.h, ub.h, c, false);
#else
    return c + (float)ua.h.x * (float)ub.h.x + (float)ua.h.y * (float)ub.h.y;
#endif
}

// ---- dtype detection ------------------------------------------------------
// Genuine bf16 RNN weights satisfy |w| <= 1/16 -> exponent field <= 122.
// An f32 buffer read as ushorts has random-mantissa words -> exponent >= 127
// appears within a few words. flag=1 -> inputs are f32.
__global__ void detect_dtype(const unsigned short* __restrict__ w, int* __restrict__ flag) {
    if (threadIdx.x == 0 && blockIdx.x == 0) {
        int f = 0;
        for (int i = 0; i < 512; ++i) {
            unsigned e = (w[i] >> 7) & 0xFF;
            if (e >= 127) f = 1;
        }
        *flag = f;
    }
}

// ---- prep: weights (bf16|f32) -> f16, bias sums -> f32, zero carries -----
__global__ void prep_w(const void* __restrict__ wih0, const void* __restrict__ whh0,
                       const void* __restrict__ bih0, const void* __restrict__ bhh0,
                       const void* __restrict__ wih1, const void* __restrict__ whh1,
                       const void* __restrict__ bih1, const void* __restrict__ bhh1,
                       _Float16* __restrict__ owih0, _Float16* __restrict__ owhh0,
                       _Float16* __restrict__ owih1, _Float16* __restrict__ owhh1,
                       float* __restrict__ obias0, float* __restrict__ obias1,
                       uint4* __restrict__ carries, const int* __restrict__ flag) {
    const bool f32 = (*flag != 0);
    int i = blockIdx.x * 256 + threadIdx.x;
    auto rd = [&](const void* p, int idx) -> float {
        return f32 ? ((const float*)p)[idx] : bf2f(((const unsigned short*)p)[idx]);
    };
    if (i < H_ * D_) owih0[i] = (_Float16)rd(wih0, i);
    if (i < H_ * H_) {
        owhh0[i] = (_Float16)rd(whh0, i);
        owih1[i] = (_Float16)rd(wih1, i);
        owhh1[i] = (_Float16)rd(whh1, i);
    }
    if (i < H_) {
        obias0[i] = rd(bih0, i) + rd(bhh0, i);
        obias1[i] = rd(bih1, i) + rd(bhh1, i);
    }
    if (i < (2 * B_ * H_) / 8) carries[i] = uint4{0, 0, 0, 0};
}

// ---- chunk projection: xw[m][j] = A_row(m) . W[j] + bias[j] --------------
// SRCX: A is the raw input x (bf16 or f32 per flag), rows (b*T_ + t0 + tc)*K.
// else: A is the f16 h0 chunk, rows m*K.
template <int K, bool SRCX>
__global__ __launch_bounds__(256, 1) void proj_chunk(const void* __restrict__ A,
                                                     const _Float16* __restrict__ W,
                                                     const float* __restrict__ bias,
                                                     _Float16* __restrict__ outx,
                                                     const int* __restrict__ flag,
                                                     int t0, int Tc) {
    constexpr int KW = K / 8;  // uint4 (8 f16) per row
    const int j = threadIdx.x;
    const long m0 = (long)blockIdx.x * 16;
    const bool f32 = SRCX && (*flag != 0);

    long arow0;
    if (SRCX) {
        long b = m0 / Tc;
        long tc0 = m0 - b * Tc;
        arow0 = (b * T_ + t0 + tc0) * (long)K;
    } else {
        arow0 = m0 * (long)K;
    }

    uint4 w[KW];
    const uint4* wp = (const uint4*)(W + (long)j * K);
#pragma unroll
    for (int i = 0; i < KW; ++i) w[i] = wp[i];

    __shared__ uint4 xt[16 * KW];
    for (int i = threadIdx.x; i < 16 * KW; i += 256) {
        int r = i / KW, c = i % KW;
        long off = arow0 + (long)r * K + (long)c * 8;  // element offset
        if (SRCX) {
            if (f32) {
                const float* s = (const float*)A + off;
                union { _Float16 h[8]; uint4 u; } r8;
#pragma unroll
                for (int q = 0; q < 8; ++q) r8.h[q] = (_Float16)s[q];
                xt[i] = r8.u;
            } else {
                xt[i] = cvt8_bf16_to_f16(*(const uint4*)((const unsigned short*)A + off));
            }
        } else {
            xt[i] = *(const uint4*)((const _Float16*)A + off);
        }
    }
    __syncthreads();

    const float bb = bias[j];
#pragma unroll 1
    for (int r = 0; r < 16; ++r) {
        const uint4* xr = xt + r * KW;
        float a0 = 0.f, a1 = 0.f, a2 = 0.f, a3 = 0.f;
#pragma unroll
        for (int i = 0; i < KW; ++i) {
            uint4 h = xr[i];   // wave-uniform LDS broadcast
            uint4 ww = w[i];
            a0 = dot2(ww.x, h.x, a0);
            a1 = dot2(ww.y, h.y, a1);
            a2 = dot2(ww.z, h.z, a2);
            a3 = dot2(ww.w, h.w, a3);
        }
        outx[(m0 + r) * H_ + j] = (_Float16)(((a0 + a1) + (a2 + a3)) + bb);
    }
}

// ---- chunk scan: one workgroup per batch, Tc sequential steps ------------
template <bool LAST>
__global__ __launch_bounds__(256, 1) void scan_chunk(const _Float16* __restrict__ xw,
                                                     const _Float16* __restrict__ Whh,
                                                     _Float16* __restrict__ carry,
                                                     _Float16* __restrict__ h0out,
                                                     void* __restrict__ out,
                                                     const int* __restrict__ flag,
                                                     int t0, int Tc) {
    const int j = threadIdx.x;
    const int b = blockIdx.x;
    const bool f32o = LAST && (*flag != 0);

    uint4 w[32];  // 256 f16 = W_hh row j
    const uint4* wp = (const uint4*)(Whh + (long)j * H_);
#pragma unroll
    for (int i = 0; i < 32; ++i) w[i] = wp[i];

    __shared__ uint4 hbuf[2][32];  // h packed f16, double-buffered
    ((_Float16*)(&hbuf[0][0]))[j] = carry[b * H_ + j];
    __syncthreads();

    const _Float16* xp = xw + (long)b * Tc * H_ + j;
    const long oidx = ((long)b * H_ + j) * T_ + t0;   // LAST: out [b][j][t]
    _Float16* hop = h0out ? h0out + (long)b * Tc * H_ + j : nullptr;

    _Float16 hf = (_Float16)0.f;
    for (int t = 0; t < Tc; ++t) {
        float xwv = (float)xp[(long)t * H_];  // issued early, consumed late
        const uint4* hb = hbuf[t & 1];
        float a0 = 0.f, a1 = 0.f, a2 = 0.f, a3 = 0.f;
#pragma unroll
        for (int i = 0; i < 32; ++i) {
            uint4 h = hb[i];  // wave-uniform LDS broadcast
            uint4 ww = w[i];
            a0 = dot2(ww.x, h.x, a0);
            a1 = dot2(ww.y, h.y, a1);
            a2 = dot2(ww.z, h.z, a2);
            a3 = dot2(ww.w, h.w, a3);
        }
        float hv = tanhf(((a0 + a1) + (a2 + a3)) + xwv);
        hf = (_Float16)hv;
        ((_Float16*)(&hbuf[(t + 1) & 1][0]))[j] = hf;
        if (LAST) {
            if (f32o) ((float*)out)[oidx + t] = hv;
            else      ((__hip_bfloat16*)out)[oidx + t] = __float2bfloat16(hv);
        } else {
            hop[(long)t * H_] = hf;  // h0 chunk [b][tc][j] f16
        }
        __syncthreads();
    }
    carry[b * H_ + j] = hf;
}

// ---------------------------------------------------------------------------
extern "C" void kernel_launch(void* const* d_in, const int* in_sizes, int n_in,
                              void* d_out, int out_size, void* d_ws, size_t ws_size,
                              hipStream_t stream) {
    const void* x    = d_in[0];
    const void* wih0 = d_in[1];
    const void* whh0 = d_in[2];
    const void* bih0 = d_in[3];
    const void* bhh0 = d_in[4];
    const void* wih1 = d_in[5];
    const void* whh1 = d_in[6];
    const void* bih1 = d_in[7];
    const void* bhh1 = d_in[8];
    (void)in_sizes; (void)n_in; (void)out_size;

    char* ws = (char*)d_ws;
    size_t off = 0;
    auto alloc = [&](size_t bytes) -> void* {
        void* p = ws + off;
        off += (bytes + 255) & ~(size_t)255;
        return p;
    };

    int*      flag    = (int*)alloc(256);
    _Float16* wih0_16 = (_Float16*)alloc((size_t)H_ * D_ * 2);
    _Float16* whh0_16 = (_Float16*)alloc((size_t)H_ * H_ * 2);
    _Float16* wih1_16 = (_Float16*)alloc((size_t)H_ * H_ * 2);
    _Float16* whh1_16 = (_Float16*)alloc((size_t)H_ * H_ * 2);
    float*    bias0   = (float*)alloc(H_ * 4);
    float*    bias1   = (float*)alloc(H_ * 4);
    _Float16* carry0  = (_Float16*)alloc((size_t)B_ * H_ * 2);
    _Float16* carry1  = (_Float16*)alloc((size_t)B_ * H_ * 2);
    size_t fixed = off;

    // largest chunk Tc (<=256) whose two chunk buffers fit in ws
    int Tc = 256;
    while (Tc > 16 && fixed + 2 * ((size_t)B_ * Tc * H_ * 2 + 256) > ws_size) Tc >>= 1;
    _Float16* xwc = (_Float16*)alloc((size_t)B_ * Tc * H_ * 2);
    _Float16* h0c = (_Float16*)alloc((size_t)B_ * Tc * H_ * 2);

    detect_dtype<<<1, 64, 0, stream>>>((const unsigned short*)whh0, flag);
    prep_w<<<(H_ * H_ + 255) / 256, 256, 0, stream>>>(
        wih0, whh0, bih0, bhh0, wih1, whh1, bih1, bhh1,
        wih0_16, whh0_16, wih1_16, whh1_16, bias0, bias1, (uint4*)carry0, flag);

    const int nproj = (B_ * Tc) / 16;
    for (int t0 = 0; t0 < T_; t0 += Tc) {
        proj_chunk<D_, true><<<nproj, 256, 0, stream>>>(x, wih0_16, bias0, xwc, flag, t0, Tc);
        scan_chunk<false><<<B_, 256, 0, stream>>>(xwc, whh0_16, carry0, h0c, nullptr, flag, t0, Tc);
        proj_chunk<H_, false><<<nproj, 256, 0, stream>>>(h0c, wih1_16, bias1, xwc, flag, t0, Tc);
        scan_chunk<true><<<B_, 256, 0, stream>>>(xwc, whh1_16, carry1, nullptr, d_out, flag, t0, Tc);
    }
}